// Round 13
// baseline (618.288 us; speedup 1.0000x reference)
//
#include <hip/hip_runtime.h>
#include <math.h>

// Problem constants
#define M_ROWS   8192     // B*S
#define N_CODES  16384
#define D_DIM    32
#define NTHREADS 256

// Certification margin (R7/R8/R9/R10/R12: absmax 0 at this margin).
// Error budget: MFMA hi/lo split |dist err| <= 3.4e-5; dropping cc (codebook
// is l2-normalized, cc = 1 +- <=4e-7) adds <=8e-7; ref ~5e-6.
// certify iff dist-gap = 2*(max1-max2) > ~7.5e-5; margin 2e-4 = 2.6x cushion.
#define DELTA_MARGIN  2e-4f

// ===== cleanup parameters =====
#define NCHUNK       16
#define CHUNK_CODES  (N_CODES / NCHUNK)       // 1024
#define SCAN_SLOTS   256                       // row-slot stride in scan grid

typedef short bf16x8 __attribute__((ext_vector_type(8)));  // 8 bf16
typedef float f32x4  __attribute__((ext_vector_type(4)));

// round-to-nearest-even fp32 -> bf16 bits
__device__ inline unsigned short bf16_rne(float f) {
    unsigned u = __float_as_uint(f);
    unsigned r = u + 0x7FFFu + ((u >> 16) & 1u);
    return (unsigned short)(r >> 16);
}

__device__ inline void pack_pair(float f0, float f1, unsigned& hi, unsigned& lo) {
    unsigned short h0 = bf16_rne(f0), h1 = bf16_rne(f1);
    float r0 = f0 - __uint_as_float((unsigned)h0 << 16);
    float r1 = f1 - __uint_as_float((unsigned)h1 << 16);
    unsigned short l0 = bf16_rne(r0), l1 = bf16_rne(r1);
    hi = (unsigned)h0 | ((unsigned)h1 << 16);
    lo = (unsigned)l0 | ((unsigned)l1 << 16);
}

// ---------------------------------------------------------------------------
// Prep+pack v3: blocks 0..63: cc[n] + codebook hi/lo bf16 pack
//               blocks 64..95: normalize z -> zn (d_out) + zz  (NO z pack --
//               vq_mfma packs its own A fragments from zn in-register)
// ---------------------------------------------------------------------------
__global__ void vq_prep_pack(const float* __restrict__ z,
                             const float* __restrict__ codebook,
                             float* __restrict__ zn, float* __restrict__ zz,
                             float* __restrict__ cc,
                             unsigned* __restrict__ chi, unsigned* __restrict__ clo,
                             int* __restrict__ todo_cnt) {
    int gid = blockIdx.x * NTHREADS + threadIdx.x;
    if (gid == 0) *todo_cnt = 0;
    if (blockIdx.x < 64) {
        const float4* r4 = reinterpret_cast<const float4*>(codebook + (size_t)gid * D_DIM);
        float4 v[8];
#pragma unroll
        for (int h = 0; h < 8; ++h) v[h] = r4[h];
        float s = 0.f;
#pragma unroll
        for (int h = 0; h < 8; ++h) {   // d = 4h+0..3, sequential (exact order)
            s = fmaf(v[h].x, v[h].x, s);
            s = fmaf(v[h].y, v[h].y, s);
            s = fmaf(v[h].z, v[h].z, s);
            s = fmaf(v[h].w, v[h].w, s);
        }
        cc[gid] = s;
#pragma unroll
        for (int h = 0; h < 8; ++h) {
            unsigned hi0, lo0, hi1, lo1;
            pack_pair(v[h].x, v[h].y, hi0, lo0);
            pack_pair(v[h].z, v[h].w, hi1, lo1);
            chi[gid * 16 + 2 * h]     = hi0;  clo[gid * 16 + 2 * h]     = lo0;
            chi[gid * 16 + 2 * h + 1] = hi1;  clo[gid * 16 + 2 * h + 1] = lo1;
        }
    } else {
        int r = gid - N_CODES;                 // 0..8191
        const float4* r4 = reinterpret_cast<const float4*>(z + (size_t)r * D_DIM);
        float4 v[8];
#pragma unroll
        for (int h = 0; h < 8; ++h) v[h] = r4[h];
        float s = 0.f;
#pragma unroll
        for (int h = 0; h < 8; ++h) {
            s = fmaf(v[h].x, v[h].x, s);
            s = fmaf(v[h].y, v[h].y, s);
            s = fmaf(v[h].z, v[h].z, s);
            s = fmaf(v[h].w, v[h].w, s);
        }
        float norm = sqrtf(s);
        norm = fmaxf(norm, 1e-12f);
        float zs = 0.f;
        float4* zn4 = reinterpret_cast<float4*>(zn + (size_t)r * D_DIM);
#pragma unroll
        for (int h = 0; h < 8; ++h) {
            float4 w;
            w.x = v[h].x / norm;               // IEEE division, matches reference
            w.y = v[h].y / norm;
            w.z = v[h].z / norm;
            w.w = v[h].w / norm;
            zn4[h] = w;
            zs = fmaf(w.x, w.x, zs);
            zs = fmaf(w.y, w.y, zs);
            zs = fmaf(w.z, w.z, zs);
            zs = fmaf(w.w, w.w, zs);
        }
        zz[r] = zs;
    }
}

// ---------------------------------------------------------------------------
// MFMA main v5 (NSLICE 16, launch_bounds(256,4)):
//  - key = RAW DOT (codebook unit-norm: cc = 1 +- 4e-7, absorbed in margin).
//    First MFMA of each chain takes a persistent zero quad as C -> NO per-pair
//    accumulator init (kills 16 accvgpr_write/v_mov per pair, R12 bottleneck).
//  - A fragments packed in-kernel from zn (fp32) -- zhi/zlo arrays removed.
//  - 4 independent 3-MFMA chains per tile-pair, step-interleaved.
//  - pair loop #pragma unroll 4 to SSA-away prefetch rotation copies.
// A: lane holds row (l&15), k=(l>>4)*8+i. D: col=l&15, row=(l>>4)*4+reg.
// ---------------------------------------------------------------------------
template <int NS>
__global__ __launch_bounds__(NTHREADS, 4)
void vq_mfma(const float* __restrict__ zn,
             const unsigned short* __restrict__ chi,
             const unsigned short* __restrict__ clo,
             float* __restrict__ pmax1, float* __restrict__ pmax2,
             int* __restrict__ pidx) {
    constexpr int SLICE_CODES = N_CODES / NS;   // 1024 at NS=16
    constexpr int NPAIR = SLICE_CODES / 32;     // 32 double-tiles

    const int tid  = threadIdx.x;
    const int wave = tid >> 6;
    const int lane = tid & 63;
    const int rb    = blockIdx.x & 63;
    const int slice = blockIdx.x >> 6;

    const int row_w = rb * 128 + wave * 32;    // wave's 32 rows (2 row-tiles)
    const int l15 = lane & 15;
    const int kg  = lane >> 4;                 // k-group 0..3
    const int kc  = kg * 8;

    // ---- pack A fragments from zn (one-time; bf16_rne identical to prep) ----
    bf16x8 a_hi0, a_lo0, a_hi1, a_lo1;
    {
        const float* zr0 = zn + (size_t)(row_w + l15) * D_DIM + kc;
        const float* zr1 = zn + (size_t)(row_w + 16 + l15) * D_DIM + kc;
        float4 f0a = *reinterpret_cast<const float4*>(zr0);
        float4 f0b = *reinterpret_cast<const float4*>(zr0 + 4);
        float4 f1a = *reinterpret_cast<const float4*>(zr1);
        float4 f1b = *reinterpret_cast<const float4*>(zr1 + 4);
        float e0[8] = {f0a.x, f0a.y, f0a.z, f0a.w, f0b.x, f0b.y, f0b.z, f0b.w};
        float e1[8] = {f1a.x, f1a.y, f1a.z, f1a.w, f1b.x, f1b.y, f1b.z, f1b.w};
#pragma unroll
        for (int j = 0; j < 8; ++j) {
            unsigned short h0 = bf16_rne(e0[j]);
            float r0 = e0[j] - __uint_as_float((unsigned)h0 << 16);
            a_hi0[j] = (short)h0;
            a_lo0[j] = (short)bf16_rne(r0);
            unsigned short h1 = bf16_rne(e1[j]);
            float r1 = e1[j] - __uint_as_float((unsigned)h1 << 16);
            a_hi1[j] = (short)h1;
            a_lo1[j] = (short)bf16_rne(r1);
        }
    }

    const f32x4 zero4 = {0.f, 0.f, 0.f, 0.f};

    float max1[8], max2[8];
    int   idx1[8];
#pragma unroll
    for (int q = 0; q < 8; ++q) { max1[q] = -3.4e38f; max2[q] = -3.4e38f; idx1[q] = 0x7FFFFFFF; }

    // argmax(top-2) update: 4 VALU per element
    auto argup = [&](const f32x4& accA, const f32x4& accB, int code) {
#pragma unroll
        for (int e = 0; e < 4; ++e) {
            float s0 = accA[e];
            max2[e] = __builtin_amdgcn_fmed3f(s0, max1[e], max2[e]);
            bool gt0 = s0 > max1[e];
            max1[e] = gt0 ? s0 : max1[e];
            idx1[e] = gt0 ? code : idx1[e];

            float s1 = accB[e];
            max2[4 + e] = __builtin_amdgcn_fmed3f(s1, max1[4 + e], max2[4 + e]);
            bool gt1 = s1 > max1[4 + e];
            max1[4 + e] = gt1 ? s1 : max1[4 + e];
            idx1[4 + e] = gt1 ? code : idx1[4 + e];
        }
    };
    // 12 MFMAs for one tile-pair: 4 independent chains of 3, step-interleaved
    auto pair_compute = [&](const bf16x8& b0h, const bf16x8& b0l,
                            const bf16x8& b1h, const bf16x8& b1l, int code) {
        f32x4 a00 = __builtin_amdgcn_mfma_f32_16x16x32_bf16(a_lo0, b0h, zero4, 0, 0, 0);
        f32x4 a01 = __builtin_amdgcn_mfma_f32_16x16x32_bf16(a_lo1, b0h, zero4, 0, 0, 0);
        f32x4 a10 = __builtin_amdgcn_mfma_f32_16x16x32_bf16(a_lo0, b1h, zero4, 0, 0, 0);
        f32x4 a11 = __builtin_amdgcn_mfma_f32_16x16x32_bf16(a_lo1, b1h, zero4, 0, 0, 0);
        a00 = __builtin_amdgcn_mfma_f32_16x16x32_bf16(a_hi0, b0l, a00, 0, 0, 0);
        a01 = __builtin_amdgcn_mfma_f32_16x16x32_bf16(a_hi1, b0l, a01, 0, 0, 0);
        a10 = __builtin_amdgcn_mfma_f32_16x16x32_bf16(a_hi0, b1l, a10, 0, 0, 0);
        a11 = __builtin_amdgcn_mfma_f32_16x16x32_bf16(a_hi1, b1l, a11, 0, 0, 0);
        a00 = __builtin_amdgcn_mfma_f32_16x16x32_bf16(a_hi0, b0h, a00, 0, 0, 0);
        a01 = __builtin_amdgcn_mfma_f32_16x16x32_bf16(a_hi1, b0h, a01, 0, 0, 0);
        a10 = __builtin_amdgcn_mfma_f32_16x16x32_bf16(a_hi0, b1h, a10, 0, 0, 0);
        a11 = __builtin_amdgcn_mfma_f32_16x16x32_bf16(a_hi1, b1h, a11, 0, 0, 0);
        argup(a00, a01, code);
        argup(a10, a11, code + 16);
    };

    // software-pipelined pair loop: prefetch p+1 during p; unroll 4 for SSA
    int code = slice * SLICE_CODES + l15;
    bf16x8 b0h = *reinterpret_cast<const bf16x8*>(chi + (size_t)code * 32 + kc);
    bf16x8 b0l = *reinterpret_cast<const bf16x8*>(clo + (size_t)code * 32 + kc);
    bf16x8 b1h = *reinterpret_cast<const bf16x8*>(chi + (size_t)(code + 16) * 32 + kc);
    bf16x8 b1l = *reinterpret_cast<const bf16x8*>(clo + (size_t)(code + 16) * 32 + kc);

#pragma unroll 4
    for (int p = 0; p < NPAIR - 1; ++p) {
        const int ncode = code + 32;
        const bf16x8 nb0h = *reinterpret_cast<const bf16x8*>(chi + (size_t)ncode * 32 + kc);
        const bf16x8 nb0l = *reinterpret_cast<const bf16x8*>(clo + (size_t)ncode * 32 + kc);
        const bf16x8 nb1h = *reinterpret_cast<const bf16x8*>(chi + (size_t)(ncode + 16) * 32 + kc);
        const bf16x8 nb1l = *reinterpret_cast<const bf16x8*>(clo + (size_t)(ncode + 16) * 32 + kc);

        pair_compute(b0h, b0l, b1h, b1l, code);

        b0h = nb0h; b0l = nb0l; b1h = nb1h; b1l = nb1l; code = ncode;
    }
    pair_compute(b0h, b0l, b1h, b1l, code);   // peeled last pair

    // merge top-2 (max) across the 16 column-lanes
#pragma unroll
    for (int q = 0; q < 8; ++q) {
        float m1 = max1[q], m2 = max2[q];
        int   i1 = idx1[q];
#pragma unroll
        for (int off = 1; off < 16; off <<= 1) {
            float o1 = __shfl_xor(m1, off);
            float o2 = __shfl_xor(m2, off);
            int   oi = __shfl_xor(i1, off);
            float nm2 = fmaxf(fminf(m1, o1), fmaxf(m2, o2));
            if (o1 > m1 || (o1 == m1 && oi < i1)) { m1 = o1; i1 = oi; }
            m2 = nm2;
        }
        max1[q] = m1; max2[q] = m2; idx1[q] = i1;
    }
    if (l15 == 0) {
#pragma unroll
        for (int q = 0; q < 8; ++q) {
            const int rt = q >> 2, e = q & 3;
            const int row = row_w + rt * 16 + kg * 4 + e;
            pmax1[slice * M_ROWS + row] = max1[q];
            pmax2[slice * M_ROWS + row] = max2[q];
            pidx [slice * M_ROWS + row] = idx1[q];
        }
    }
}

// ---------------------------------------------------------------------------
// Merge slices (max-key = raw dot); certified rows finalize; rest -> todo.
// dist-gap = 2*(key1 - key2); slices ascend in code => strict > keeps lowest.
// ---------------------------------------------------------------------------
template <int NS>
__global__ void vq_merge(const float* __restrict__ codebook,
                         const float* __restrict__ pmax1,
                         const float* __restrict__ pmax2,
                         const int* __restrict__ pidx,
                         float* __restrict__ zq, float* __restrict__ idx_out,
                         int* __restrict__ todo_cnt, int* __restrict__ todo) {
    const int row = blockIdx.x * NTHREADS + threadIdx.x;
    float m1 = pmax1[row], m2 = pmax2[row];
    int   i1 = pidx[row];
#pragma unroll
    for (int s = 1; s < NS; ++s) {
        float o1 = pmax1[s * M_ROWS + row];
        float o2 = pmax2[s * M_ROWS + row];
        int   oi = pidx [s * M_ROWS + row];
        float nm2 = fmaxf(fminf(m1, o1), fmaxf(m2, o2));
        if (o1 > m1) { m1 = o1; i1 = oi; }
        m2 = nm2;
    }
    if (2.0f * (m1 - m2) > DELTA_MARGIN) {
        idx_out[row] = (float)i1;
        const float4* src = reinterpret_cast<const float4*>(codebook + (size_t)i1 * D_DIM);
        float4* dst = reinterpret_cast<float4*>(zq + (size_t)row * D_DIM);
#pragma unroll
        for (int k = 0; k < 8; ++k) dst[k] = src[k];
    } else {
        int p = atomicAdd(todo_cnt, 1);
        todo[p] = row;
    }
}

// ---------------------------------------------------------------------------
// Cleanup SCAN (R8-validated): work item = (todo-slot, chunk). Exact fp32.
// ---------------------------------------------------------------------------
__global__ __launch_bounds__(NTHREADS)
void vq_cleanup_scan(const float* __restrict__ zn, const float* __restrict__ zz,
                     const float* __restrict__ codebook, const float* __restrict__ cc,
                     const int* __restrict__ todo_cnt, const int* __restrict__ todo,
                     float* __restrict__ cpmin, int* __restrict__ cpidx) {
    const int n = *todo_cnt;
    const int chunk = blockIdx.x & (NCHUNK - 1);
    const int slot  = blockIdx.x >> 4;            // 0..SCAN_SLOTS-1
    const int tid   = threadIdx.x;
    const int cbase = chunk * CHUNK_CODES;

    __shared__ float sv[4];
    __shared__ int   si[4];

    for (int i = slot; i < n; i += SCAN_SLOTS) {
        const int row = todo[i];

        float zr[D_DIM];
#pragma unroll
        for (int d = 0; d < D_DIM; ++d) zr[d] = zn[(size_t)row * D_DIM + d];
        const float zzv = zz[row];

        float bm = 3.4e38f;
        int   bi = 0x7FFFFFFF;
#pragma unroll
        for (int k = 0; k < CHUNK_CODES / NTHREADS; ++k) {   // 4 iters
            const int c = cbase + tid + (k << 8);            // ascending per thread
            const float4* cb = reinterpret_cast<const float4*>(codebook + (size_t)c * D_DIM);
            float dot = 0.f;
#pragma unroll
            for (int h = 0; h < 8; ++h) {
                float4 v = cb[h];
                dot = fmaf(zr[4 * h + 0], v.x, dot);
                dot = fmaf(zr[4 * h + 1], v.y, dot);
                dot = fmaf(zr[4 * h + 2], v.z, dot);
                dot = fmaf(zr[4 * h + 3], v.w, dot);
            }
            float t = zzv + cc[c];
            float dist = fmaf(-2.f, dot, t);
            if (dist < bm || (dist == bm && c < bi)) { bm = dist; bi = c; }
        }

#pragma unroll
        for (int off = 32; off >= 1; off >>= 1) {
            float ov = __shfl_xor(bm, off);
            int   oi = __shfl_xor(bi, off);
            if (ov < bm || (ov == bm && oi < bi)) { bm = ov; bi = oi; }
        }
        if ((tid & 63) == 0) { sv[tid >> 6] = bm; si[tid >> 6] = bi; }
        __syncthreads();
        if (tid == 0) {
            float v = sv[0]; int idx = si[0];
#pragma unroll
            for (int w = 1; w < 4; ++w) {
                if (sv[w] < v || (sv[w] == v && si[w] < idx)) { v = sv[w]; idx = si[w]; }
            }
            cpmin[chunk * M_ROWS + row] = v;
            cpidx[chunk * M_ROWS + row] = idx;
        }
        __syncthreads();
    }
}

// ---------------------------------------------------------------------------
// Cleanup FINAL (R8-validated): one thread per todo row.
// ---------------------------------------------------------------------------
__global__ __launch_bounds__(NTHREADS)
void vq_cleanup_final(const float* __restrict__ codebook,
                      const int* __restrict__ todo_cnt, const int* __restrict__ todo,
                      const float* __restrict__ cpmin, const int* __restrict__ cpidx,
                      float* __restrict__ zq, float* __restrict__ idx_out) {
    const int n = *todo_cnt;
    for (int i = blockIdx.x * NTHREADS + threadIdx.x; i < n; i += gridDim.x * NTHREADS) {
        const int row = todo[i];
        float bv = cpmin[row];
        int   bi = cpidx[row];
#pragma unroll
        for (int c = 1; c < NCHUNK; ++c) {
            float v = cpmin[c * M_ROWS + row];
            int   j = cpidx[c * M_ROWS + row];
            if (v < bv || (v == bv && j < bi)) { bv = v; bi = j; }
        }
        idx_out[row] = (float)bi;
        const float4* src = reinterpret_cast<const float4*>(codebook + (size_t)bi * D_DIM);
        float4* dst = reinterpret_cast<float4*>(zq + (size_t)row * D_DIM);
#pragma unroll
        for (int k = 0; k < 8; ++k) dst[k] = src[k];
    }
}

// ===========================================================================
// ===== Fallback path (verbatim R3, proven 175 us / absmax 0) ==============
// ===========================================================================
#define R_TILE   32
#define NSLICE_F 4
#define SLICE_CODES_F (N_CODES / NSLICE_F)
#define C_TILE   256
#define N_TILES_F (SLICE_CODES_F / C_TILE)
#define CB_PAD   36

__global__ void vq_prep_basic(const float* __restrict__ z,
                              const float* __restrict__ codebook,
                              float* __restrict__ zn,
                              float* __restrict__ zz,
                              float* __restrict__ cc) {
    int gid = blockIdx.x * NTHREADS + threadIdx.x;
    if (blockIdx.x < 64) {
        const float* row = codebook + (size_t)gid * D_DIM;
        float s = 0.f;
#pragma unroll
        for (int d = 0; d < D_DIM; ++d) s = fmaf(row[d], row[d], s);
        cc[gid] = s;
    } else {
        int r = gid - N_CODES;
        const float* row = z + (size_t)r * D_DIM;
        float s = 0.f;
#pragma unroll
        for (int d = 0; d < D_DIM; ++d) { float v = row[d]; s = fmaf(v, v, s); }
        float norm = sqrtf(s);
        norm = fmaxf(norm, 1e-12f);
        float zs = 0.f;
#pragma unroll
        for (int d = 0; d < D_DIM; ++d) {
            float v = row[d] / norm;
            zn[(size_t)r * D_DIM + d] = v;
            zs = fmaf(v, v, zs);
        }
        zz[r] = zs;
    }
}

__global__ __launch_bounds__(NTHREADS, 4)
void vq_main_basic(const float* __restrict__ zn, const float* __restrict__ zz,
                   const float* __restrict__ codebook, const float* __restrict__ cc,
                   float* __restrict__ pminv, int* __restrict__ pmini) {
    __shared__ float cb_lds[C_TILE * CB_PAD];
    __shared__ float zt[R_TILE * D_DIM];
    const int tid = threadIdx.x;
    const int rb = blockIdx.x & 255;
    const int slice = blockIdx.x >> 8;
    const int rg = tid >> 6;
    const int cg = tid & 63;
    const int row_base = rb * R_TILE;
    const int code_base = slice * SLICE_CODES_F;
    const int wrow = row_base + rg * 8;
    {
        float4 v = *reinterpret_cast<const float4*>(zn + (size_t)row_base * D_DIM + tid * 4);
        *reinterpret_cast<float4*>(&zt[tid * 4]) = v;
    }
    float zzr[8];
#pragma unroll
    for (int r = 0; r < 8; ++r) zzr[r] = zz[wrow + r];
    float minv[8]; int mini[8];
#pragma unroll
    for (int r = 0; r < 8; ++r) { minv[r] = 3.4e38f; mini[r] = 0; }
    for (int t = 0; t < N_TILES_F; ++t) {
        const int base = code_base + t * C_TILE;
        __syncthreads();
        {
            const float4* src = reinterpret_cast<const float4*>(codebook + (size_t)(base + tid) * D_DIM);
            float* dstf = &cb_lds[tid * CB_PAD];
#pragma unroll
            for (int k = 0; k < 8; ++k) *reinterpret_cast<float4*>(dstf + k * 4) = src[k];
        }
        __syncthreads();
        float acc[8][4];
#pragma unroll
        for (int r = 0; r < 8; ++r)
#pragma unroll
            for (int j = 0; j < 4; ++j) acc[r][j] = 0.f;
#pragma unroll
        for (int dc = 0; dc < 8; ++dc) {
            float4 cb4[4];
#pragma unroll
            for (int j = 0; j < 4; ++j)
                cb4[j] = *reinterpret_cast<const float4*>(&cb_lds[(cg + 64 * j) * CB_PAD + dc * 4]);
#pragma unroll
            for (int r = 0; r < 8; ++r) {
                const float4 zv = *reinterpret_cast<const float4*>(&zt[(rg * 8 + r) * D_DIM + dc * 4]);
#pragma unroll
                for (int j = 0; j < 4; ++j) {
                    float a = acc[r][j];
                    a = fmaf(zv.x, cb4[j].x, a);
                    a = fmaf(zv.y, cb4[j].y, a);
                    a = fmaf(zv.z, cb4[j].z, a);
                    a = fmaf(zv.w, cb4[j].w, a);
                    acc[r][j] = a;
                }
            }
        }
#pragma unroll
        for (int j = 0; j < 4; ++j) {
            const int code = base + cg + 64 * j;
            const float ccj = cc[code];
#pragma unroll
            for (int r = 0; r < 8; ++r) {
                float tsum = zzr[r] + ccj;
                float dist = fmaf(-2.f, acc[r][j], tsum);
                if (dist < minv[r]) { minv[r] = dist; mini[r] = code; }
            }
        }
    }
#pragma unroll
    for (int r = 0; r < 8; ++r) {
        float v = minv[r]; int i = mini[r];
#pragma unroll
        for (int off = 32; off >= 1; off >>= 1) {
            float ov = __shfl_xor(v, off);
            int   oi = __shfl_xor(i, off);
            if (ov < v || (ov == v && oi < i)) { v = ov; i = oi; }
        }
        minv[r] = v; mini[r] = i;
    }
    if (cg == 0) {
#pragma unroll
        for (int r = 0; r < 8; ++r) {
            pminv[slice * M_ROWS + wrow + r] = minv[r];
            pmini[slice * M_ROWS + wrow + r] = mini[r];
        }
    }
}

__global__ void vq_final_basic(const float* __restrict__ codebook,
                               const float* __restrict__ pminv,
                               const int* __restrict__ pmini,
                               float* __restrict__ zq, float* __restrict__ idx_out) {
    int row = blockIdx.x * NTHREADS + threadIdx.x;
    float bv = pminv[row];
    int   bi = pmini[row];
#pragma unroll
    for (int s = 1; s < NSLICE_F; ++s) {
        float v = pminv[s * M_ROWS + row];
        int   i = pmini[s * M_ROWS + row];
        if (v < bv || (v == bv && i < bi)) { bv = v; bi = i; }
    }
    idx_out[row] = (float)bi;
    const float4* src = reinterpret_cast<const float4*>(codebook + (size_t)bi * D_DIM);
    float4* dst = reinterpret_cast<float4*>(zq + (size_t)row * D_DIM);
#pragma unroll
    for (int k = 0; k < 8; ++k) dst[k] = src[k];
}

// ===========================================================================
static size_t ws_needed(int nslice) {
    return 4ull * (N_CODES + M_ROWS + 3ull * (size_t)nslice * M_ROWS) +
           4ull * (4 + M_ROWS) +
           2ull * (2ull * N_CODES * D_DIM) + 4096 /*slack*/;
}

template <int NS>
static void launch_mfma_path(const float* z, const float* codebook,
                             float* zn, float* zq_out, float* idx_out,
                             void* d_ws, hipStream_t stream) {
    float* cc    = (float*)d_ws;
    float* zz    = cc + N_CODES;
    float* pmax1 = zz + M_ROWS;
    float* pmax2 = pmax1 + (size_t)NS * M_ROWS;
    int*   pidx  = (int*)(pmax2 + (size_t)NS * M_ROWS);
    int*   todo_cnt = pidx + (size_t)NS * M_ROWS;
    int*   todo  = todo_cnt + 4;
    unsigned* chi = (unsigned*)(todo + M_ROWS);
    unsigned* clo = chi + (size_t)N_CODES * D_DIM / 2;

    // cleanup partials reuse pmax1/pidx (consumed by vq_merge before scan)
    float* cpmin = pmax1;
    int*   cpidx = pidx;

    vq_prep_pack<<<96, NTHREADS, 0, stream>>>(z, codebook, zn, zz, cc,
                                              chi, clo, todo_cnt);
    vq_mfma<NS><<<64 * NS, NTHREADS, 0, stream>>>(
        zn, (const unsigned short*)chi, (const unsigned short*)clo,
        pmax1, pmax2, pidx);
    vq_merge<NS><<<M_ROWS / NTHREADS, NTHREADS, 0, stream>>>(
        codebook, pmax1, pmax2, pidx, zq_out, idx_out, todo_cnt, todo);
    vq_cleanup_scan<<<SCAN_SLOTS * NCHUNK, NTHREADS, 0, stream>>>(
        zn, zz, codebook, cc, todo_cnt, todo, cpmin, cpidx);
    vq_cleanup_final<<<32, NTHREADS, 0, stream>>>(
        codebook, todo_cnt, todo, cpmin, cpidx, zq_out, idx_out);
}

extern "C" void kernel_launch(void* const* d_in, const int* in_sizes, int n_in,
                              void* d_out, int out_size, void* d_ws, size_t ws_size,
                              hipStream_t stream) {
    const float* z        = (const float*)d_in[0];   // [8,1024,32]
    const float* codebook = (const float*)d_in[1];   // [16384,32]

    float* out     = (float*)d_out;
    float* zq_out  = out;                            // 262144 floats
    float* idx_out = out + (size_t)M_ROWS * D_DIM;   // 8192 floats
    float* zn      = zq_out;                         // zn lives in zq region

    if (ws_size >= ws_needed(16)) {
        launch_mfma_path<16>(z, codebook, zn, zq_out, idx_out, d_ws, stream);
    } else {
        // Fallback: proven R3 path (~350 KB ws)
        float* cc    = (float*)d_ws;
        float* zz    = cc + N_CODES;
        float* pminv = zz + M_ROWS;
        int*   pmini = (int*)(pminv + (size_t)NSLICE_F * M_ROWS);

        vq_prep_basic<<<96, NTHREADS, 0, stream>>>(z, codebook, zn, zz, cc);
        vq_main_basic<<<256 * NSLICE_F, NTHREADS, 0, stream>>>(zn, zz, codebook, cc,
                                                               pminv, pmini);
        vq_final_basic<<<M_ROWS / NTHREADS, NTHREADS, 0, stream>>>(codebook, pminv,
                                                                   pmini, zq_out, idx_out);
    }
}

// Round 14
// 73.819 us; speedup vs baseline: 8.3758x; 8.3758x over previous
//
#include <hip/hip_runtime.h>
#include <math.h>

// Problem constants
#define M_ROWS   8192     // B*S
#define N_CODES  16384
#define D_DIM    32
#define NTHREADS 256

// Certification margin (R7/R8/R10/R12: absmax 0 at this margin).
// Error budget: hi/lo-split MFMA |dist err| <= ~3e-5; raw-dot key (codebook
// unit-norm, cc = 1 +- 4e-7) adds <= 8e-7; ref ~5e-6.
// certify iff dist-gap = 2*(max1-max2) > ~7e-5; margin 2e-4 = 2.8x cushion.
#define DELTA_MARGIN  2e-4f

// ===== cleanup parameters =====
#define NCHUNK       16
#define CHUNK_CODES  (N_CODES / NCHUNK)       // 1024
#define SCAN_SLOTS   256                       // row-slot stride in scan grid

typedef short bf16x8 __attribute__((ext_vector_type(8)));  // 8 bf16
typedef float f32x4  __attribute__((ext_vector_type(4)));

// round-to-nearest-even fp32 -> bf16 bits
__device__ inline unsigned short bf16_rne(float f) {
    unsigned u = __float_as_uint(f);
    unsigned r = u + 0x7FFFu + ((u >> 16) & 1u);
    return (unsigned short)(r >> 16);
}

__device__ inline void pack_pair(float f0, float f1, unsigned& hi, unsigned& lo) {
    unsigned short h0 = bf16_rne(f0), h1 = bf16_rne(f1);
    float r0 = f0 - __uint_as_float((unsigned)h0 << 16);
    float r1 = f1 - __uint_as_float((unsigned)h1 << 16);
    unsigned short l0 = bf16_rne(r0), l1 = bf16_rne(r1);
    hi = (unsigned)h0 | ((unsigned)h1 << 16);
    lo = (unsigned)l0 | ((unsigned)l1 << 16);
}

// ---------------------------------------------------------------------------
// Prep+pack (R12-validated, minus cch): blocks 0..63: cc + codebook hi/lo pack
//   blocks 64..95: normalize z -> zn (d_out), zz, z hi/lo pack
// ---------------------------------------------------------------------------
__global__ void vq_prep_pack(const float* __restrict__ z,
                             const float* __restrict__ codebook,
                             float* __restrict__ zn, float* __restrict__ zz,
                             float* __restrict__ cc,
                             unsigned* __restrict__ chi, unsigned* __restrict__ clo,
                             unsigned* __restrict__ zhi, unsigned* __restrict__ zlo,
                             int* __restrict__ todo_cnt) {
    int gid = blockIdx.x * NTHREADS + threadIdx.x;
    if (gid == 0) *todo_cnt = 0;
    if (blockIdx.x < 64) {
        const float4* r4 = reinterpret_cast<const float4*>(codebook + (size_t)gid * D_DIM);
        float4 v[8];
#pragma unroll
        for (int h = 0; h < 8; ++h) v[h] = r4[h];
        float s = 0.f;
#pragma unroll
        for (int h = 0; h < 8; ++h) {   // d = 4h+0..3, sequential (exact order)
            s = fmaf(v[h].x, v[h].x, s);
            s = fmaf(v[h].y, v[h].y, s);
            s = fmaf(v[h].z, v[h].z, s);
            s = fmaf(v[h].w, v[h].w, s);
        }
        cc[gid] = s;
#pragma unroll
        for (int h = 0; h < 8; ++h) {
            unsigned hi0, lo0, hi1, lo1;
            pack_pair(v[h].x, v[h].y, hi0, lo0);
            pack_pair(v[h].z, v[h].w, hi1, lo1);
            chi[gid * 16 + 2 * h]     = hi0;  clo[gid * 16 + 2 * h]     = lo0;
            chi[gid * 16 + 2 * h + 1] = hi1;  clo[gid * 16 + 2 * h + 1] = lo1;
        }
    } else {
        int r = gid - N_CODES;                 // 0..8191
        const float4* r4 = reinterpret_cast<const float4*>(z + (size_t)r * D_DIM);
        float4 v[8];
#pragma unroll
        for (int h = 0; h < 8; ++h) v[h] = r4[h];
        float s = 0.f;
#pragma unroll
        for (int h = 0; h < 8; ++h) {
            s = fmaf(v[h].x, v[h].x, s);
            s = fmaf(v[h].y, v[h].y, s);
            s = fmaf(v[h].z, v[h].z, s);
            s = fmaf(v[h].w, v[h].w, s);
        }
        float norm = sqrtf(s);
        norm = fmaxf(norm, 1e-12f);
        float zs = 0.f;
        float4* zn4 = reinterpret_cast<float4*>(zn + (size_t)r * D_DIM);
#pragma unroll
        for (int h = 0; h < 8; ++h) {
            float4 w;
            w.x = v[h].x / norm;               // IEEE division, matches reference
            w.y = v[h].y / norm;
            w.z = v[h].z / norm;
            w.w = v[h].w / norm;
            zn4[h] = w;
            zs = fmaf(w.x, w.x, zs);
            zs = fmaf(w.y, w.y, zs);
            zs = fmaf(w.z, w.z, zs);
            zs = fmaf(w.w, w.w, zs);
            v[h] = w;                          // keep normalized for packing
        }
        zz[r] = zs;
#pragma unroll
        for (int h = 0; h < 8; ++h) {
            unsigned hi0, lo0, hi1, lo1;
            pack_pair(v[h].x, v[h].y, hi0, lo0);
            pack_pair(v[h].z, v[h].w, hi1, lo1);
            zhi[r * 16 + 2 * h]     = hi0;  zlo[r * 16 + 2 * h]     = lo0;
            zhi[r * 16 + 2 * h + 1] = hi1;  zlo[r * 16 + 2 * h + 1] = lo1;
        }
    }
}

// ---------------------------------------------------------------------------
// MFMA main v6 (R12 structure, controlled delta):
//  - key = RAW DOT (codebook unit-norm; margin covers the 4e-7 cc wobble).
//  - First MFMA of each chain takes a persistent zero quad as the C operand
//    -> zero per-pair accumulator-init instructions (R12's measured overhead).
//  - NO cch loads. Prefetch depth 1 pair. NO unroll pragma (R13 spill lesson).
// A: lane holds row (l&15), k=(l>>4)*8+i. D: col=l&15, row=(l>>4)*4+reg.
// ---------------------------------------------------------------------------
template <int NS>
__global__ __launch_bounds__(NTHREADS, 4)
void vq_mfma(const unsigned short* __restrict__ zhi,
             const unsigned short* __restrict__ zlo,
             const unsigned short* __restrict__ chi,
             const unsigned short* __restrict__ clo,
             float* __restrict__ pmax1, float* __restrict__ pmax2,
             int* __restrict__ pidx) {
    constexpr int SLICE_CODES = N_CODES / NS;   // 1024 at NS=16
    constexpr int NPAIR = SLICE_CODES / 32;     // 32 double-tiles

    const int tid  = threadIdx.x;
    const int wave = tid >> 6;
    const int lane = tid & 63;
    const int rb    = blockIdx.x & 63;
    const int slice = blockIdx.x >> 6;

    const int row_w = rb * 128 + wave * 32;    // wave's 32 rows (2 row-tiles)
    const int l15 = lane & 15;
    const int kg  = lane >> 4;                 // k-group 0..3
    const int kc  = kg * 8;

    const bf16x8 a_hi0 = *reinterpret_cast<const bf16x8*>(zhi + (size_t)(row_w + l15) * 32 + kc);
    const bf16x8 a_lo0 = *reinterpret_cast<const bf16x8*>(zlo + (size_t)(row_w + l15) * 32 + kc);
    const bf16x8 a_hi1 = *reinterpret_cast<const bf16x8*>(zhi + (size_t)(row_w + 16 + l15) * 32 + kc);
    const bf16x8 a_lo1 = *reinterpret_cast<const bf16x8*>(zlo + (size_t)(row_w + 16 + l15) * 32 + kc);

    const f32x4 zero4 = {0.f, 0.f, 0.f, 0.f};

    float max1[8], max2[8];
    int   idx1[8];
#pragma unroll
    for (int q = 0; q < 8; ++q) { max1[q] = -3.4e38f; max2[q] = -3.4e38f; idx1[q] = 0x7FFFFFFF; }

    // argmax(top-2) update: 4 VALU per element
    auto argup = [&](const f32x4& accA, const f32x4& accB, int code) {
#pragma unroll
        for (int e = 0; e < 4; ++e) {
            float s0 = accA[e];
            max2[e] = __builtin_amdgcn_fmed3f(s0, max1[e], max2[e]);
            bool gt0 = s0 > max1[e];
            max1[e] = gt0 ? s0 : max1[e];
            idx1[e] = gt0 ? code : idx1[e];

            float s1 = accB[e];
            max2[4 + e] = __builtin_amdgcn_fmed3f(s1, max1[4 + e], max2[4 + e]);
            bool gt1 = s1 > max1[4 + e];
            max1[4 + e] = gt1 ? s1 : max1[4 + e];
            idx1[4 + e] = gt1 ? code : idx1[4 + e];
        }
    };
    // 12 MFMAs for one tile-pair: 4 independent chains of 3, step-interleaved;
    // first MFMA of each chain reads zero4 directly as C (no init instr).
    auto pair_compute = [&](const bf16x8& b0h, const bf16x8& b0l,
                            const bf16x8& b1h, const bf16x8& b1l, int code) {
        f32x4 a00 = __builtin_amdgcn_mfma_f32_16x16x32_bf16(a_lo0, b0h, zero4, 0, 0, 0);
        f32x4 a01 = __builtin_amdgcn_mfma_f32_16x16x32_bf16(a_lo1, b0h, zero4, 0, 0, 0);
        f32x4 a10 = __builtin_amdgcn_mfma_f32_16x16x32_bf16(a_lo0, b1h, zero4, 0, 0, 0);
        f32x4 a11 = __builtin_amdgcn_mfma_f32_16x16x32_bf16(a_lo1, b1h, zero4, 0, 0, 0);
        a00 = __builtin_amdgcn_mfma_f32_16x16x32_bf16(a_hi0, b0l, a00, 0, 0, 0);
        a01 = __builtin_amdgcn_mfma_f32_16x16x32_bf16(a_hi1, b0l, a01, 0, 0, 0);
        a10 = __builtin_amdgcn_mfma_f32_16x16x32_bf16(a_hi0, b1l, a10, 0, 0, 0);
        a11 = __builtin_amdgcn_mfma_f32_16x16x32_bf16(a_hi1, b1l, a11, 0, 0, 0);
        a00 = __builtin_amdgcn_mfma_f32_16x16x32_bf16(a_hi0, b0h, a00, 0, 0, 0);
        a01 = __builtin_amdgcn_mfma_f32_16x16x32_bf16(a_hi1, b0h, a01, 0, 0, 0);
        a10 = __builtin_amdgcn_mfma_f32_16x16x32_bf16(a_hi0, b1h, a10, 0, 0, 0);
        a11 = __builtin_amdgcn_mfma_f32_16x16x32_bf16(a_hi1, b1h, a11, 0, 0, 0);
        argup(a00, a01, code);
        argup(a10, a11, code + 16);
    };

    // software-pipelined pair loop: prefetch p+1 during p (R10/R12-proven)
    int code = slice * SLICE_CODES + l15;
    bf16x8 b0h = *reinterpret_cast<const bf16x8*>(chi + (size_t)code * 32 + kc);
    bf16x8 b0l = *reinterpret_cast<const bf16x8*>(clo + (size_t)code * 32 + kc);
    bf16x8 b1h = *reinterpret_cast<const bf16x8*>(chi + (size_t)(code + 16) * 32 + kc);
    bf16x8 b1l = *reinterpret_cast<const bf16x8*>(clo + (size_t)(code + 16) * 32 + kc);

    for (int p = 0; p < NPAIR - 1; ++p) {
        const int ncode = code + 32;
        const bf16x8 nb0h = *reinterpret_cast<const bf16x8*>(chi + (size_t)ncode * 32 + kc);
        const bf16x8 nb0l = *reinterpret_cast<const bf16x8*>(clo + (size_t)ncode * 32 + kc);
        const bf16x8 nb1h = *reinterpret_cast<const bf16x8*>(chi + (size_t)(ncode + 16) * 32 + kc);
        const bf16x8 nb1l = *reinterpret_cast<const bf16x8*>(clo + (size_t)(ncode + 16) * 32 + kc);

        pair_compute(b0h, b0l, b1h, b1l, code);

        b0h = nb0h; b0l = nb0l; b1h = nb1h; b1l = nb1l; code = ncode;
    }
    pair_compute(b0h, b0l, b1h, b1l, code);   // peeled last pair

    // merge top-2 (max) across the 16 column-lanes
#pragma unroll
    for (int q = 0; q < 8; ++q) {
        float m1 = max1[q], m2 = max2[q];
        int   i1 = idx1[q];
#pragma unroll
        for (int off = 1; off < 16; off <<= 1) {
            float o1 = __shfl_xor(m1, off);
            float o2 = __shfl_xor(m2, off);
            int   oi = __shfl_xor(i1, off);
            float nm2 = fmaxf(fminf(m1, o1), fmaxf(m2, o2));
            if (o1 > m1 || (o1 == m1 && oi < i1)) { m1 = o1; i1 = oi; }
            m2 = nm2;
        }
        max1[q] = m1; max2[q] = m2; idx1[q] = i1;
    }
    if (l15 == 0) {
#pragma unroll
        for (int q = 0; q < 8; ++q) {
            const int rt = q >> 2, e = q & 3;
            const int row = row_w + rt * 16 + kg * 4 + e;
            pmax1[slice * M_ROWS + row] = max1[q];
            pmax2[slice * M_ROWS + row] = max2[q];
            pidx [slice * M_ROWS + row] = idx1[q];
        }
    }
}

// ---------------------------------------------------------------------------
// Merge slices (max-key = raw dot, R12-validated merge algebra); certified
// rows finalize; rest -> todo.
// ---------------------------------------------------------------------------
template <int NS>
__global__ void vq_merge(const float* __restrict__ codebook,
                         const float* __restrict__ pmax1,
                         const float* __restrict__ pmax2,
                         const int* __restrict__ pidx,
                         float* __restrict__ zq, float* __restrict__ idx_out,
                         int* __restrict__ todo_cnt, int* __restrict__ todo) {
    const int row = blockIdx.x * NTHREADS + threadIdx.x;
    float m1 = pmax1[row], m2 = pmax2[row];
    int   i1 = pidx[row];
#pragma unroll
    for (int s = 1; s < NS; ++s) {
        float o1 = pmax1[s * M_ROWS + row];
        float o2 = pmax2[s * M_ROWS + row];
        int   oi = pidx [s * M_ROWS + row];
        float nm2 = fmaxf(fminf(m1, o1), fmaxf(m2, o2));
        if (o1 > m1) { m1 = o1; i1 = oi; }
        m2 = nm2;
    }
    if (2.0f * (m1 - m2) > DELTA_MARGIN) {
        idx_out[row] = (float)i1;
        const float4* src = reinterpret_cast<const float4*>(codebook + (size_t)i1 * D_DIM);
        float4* dst = reinterpret_cast<float4*>(zq + (size_t)row * D_DIM);
#pragma unroll
        for (int k = 0; k < 8; ++k) dst[k] = src[k];
    } else {
        int p = atomicAdd(todo_cnt, 1);
        todo[p] = row;
    }
}

// ---------------------------------------------------------------------------
// Cleanup SCAN (R8-validated): work item = (todo-slot, chunk). Exact fp32.
// ---------------------------------------------------------------------------
__global__ __launch_bounds__(NTHREADS)
void vq_cleanup_scan(const float* __restrict__ zn, const float* __restrict__ zz,
                     const float* __restrict__ codebook, const float* __restrict__ cc,
                     const int* __restrict__ todo_cnt, const int* __restrict__ todo,
                     float* __restrict__ cpmin, int* __restrict__ cpidx) {
    const int n = *todo_cnt;
    const int chunk = blockIdx.x & (NCHUNK - 1);
    const int slot  = blockIdx.x >> 4;            // 0..SCAN_SLOTS-1
    const int tid   = threadIdx.x;
    const int cbase = chunk * CHUNK_CODES;

    __shared__ float sv[4];
    __shared__ int   si[4];

    for (int i = slot; i < n; i += SCAN_SLOTS) {
        const int row = todo[i];

        float zr[D_DIM];
#pragma unroll
        for (int d = 0; d < D_DIM; ++d) zr[d] = zn[(size_t)row * D_DIM + d];
        const float zzv = zz[row];

        float bm = 3.4e38f;
        int   bi = 0x7FFFFFFF;
#pragma unroll
        for (int k = 0; k < CHUNK_CODES / NTHREADS; ++k) {   // 4 iters
            const int c = cbase + tid + (k << 8);            // ascending per thread
            const float4* cb = reinterpret_cast<const float4*>(codebook + (size_t)c * D_DIM);
            float dot = 0.f;
#pragma unroll
            for (int h = 0; h < 8; ++h) {
                float4 v = cb[h];
                dot = fmaf(zr[4 * h + 0], v.x, dot);
                dot = fmaf(zr[4 * h + 1], v.y, dot);
                dot = fmaf(zr[4 * h + 2], v.z, dot);
                dot = fmaf(zr[4 * h + 3], v.w, dot);
            }
            float t = zzv + cc[c];
            float dist = fmaf(-2.f, dot, t);
            if (dist < bm || (dist == bm && c < bi)) { bm = dist; bi = c; }
        }

#pragma unroll
        for (int off = 32; off >= 1; off >>= 1) {
            float ov = __shfl_xor(bm, off);
            int   oi = __shfl_xor(bi, off);
            if (ov < bm || (ov == bm && oi < bi)) { bm = ov; bi = oi; }
        }
        if ((tid & 63) == 0) { sv[tid >> 6] = bm; si[tid >> 6] = bi; }
        __syncthreads();
        if (tid == 0) {
            float v = sv[0]; int idx = si[0];
#pragma unroll
            for (int w = 1; w < 4; ++w) {
                if (sv[w] < v || (sv[w] == v && si[w] < idx)) { v = sv[w]; idx = si[w]; }
            }
            cpmin[chunk * M_ROWS + row] = v;
            cpidx[chunk * M_ROWS + row] = idx;
        }
        __syncthreads();
    }
}

// ---------------------------------------------------------------------------
// Cleanup FINAL (R8-validated): one thread per todo row.
// ---------------------------------------------------------------------------
__global__ __launch_bounds__(NTHREADS)
void vq_cleanup_final(const float* __restrict__ codebook,
                      const int* __restrict__ todo_cnt, const int* __restrict__ todo,
                      const float* __restrict__ cpmin, const int* __restrict__ cpidx,
                      float* __restrict__ zq, float* __restrict__ idx_out) {
    const int n = *todo_cnt;
    for (int i = blockIdx.x * NTHREADS + threadIdx.x; i < n; i += gridDim.x * NTHREADS) {
        const int row = todo[i];
        float bv = cpmin[row];
        int   bi = cpidx[row];
#pragma unroll
        for (int c = 1; c < NCHUNK; ++c) {
            float v = cpmin[c * M_ROWS + row];
            int   j = cpidx[c * M_ROWS + row];
            if (v < bv || (v == bv && j < bi)) { bv = v; bi = j; }
        }
        idx_out[row] = (float)bi;
        const float4* src = reinterpret_cast<const float4*>(codebook + (size_t)bi * D_DIM);
        float4* dst = reinterpret_cast<float4*>(zq + (size_t)row * D_DIM);
#pragma unroll
        for (int k = 0; k < 8; ++k) dst[k] = src[k];
    }
}

// ===========================================================================
// ===== Fallback path (verbatim R3, proven 175 us / absmax 0) ==============
// ===========================================================================
#define R_TILE   32
#define NSLICE_F 4
#define SLICE_CODES_F (N_CODES / NSLICE_F)
#define C_TILE   256
#define N_TILES_F (SLICE_CODES_F / C_TILE)
#define CB_PAD   36

__global__ void vq_prep_basic(const float* __restrict__ z,
                              const float* __restrict__ codebook,
                              float* __restrict__ zn,
                              float* __restrict__ zz,
                              float* __restrict__ cc) {
    int gid = blockIdx.x * NTHREADS + threadIdx.x;
    if (blockIdx.x < 64) {
        const float* row = codebook + (size_t)gid * D_DIM;
        float s = 0.f;
#pragma unroll
        for (int d = 0; d < D_DIM; ++d) s = fmaf(row[d], row[d], s);
        cc[gid] = s;
    } else {
        int r = gid - N_CODES;
        const float* row = z + (size_t)r * D_DIM;
        float s = 0.f;
#pragma unroll
        for (int d = 0; d < D_DIM; ++d) { float v = row[d]; s = fmaf(v, v, s); }
        float norm = sqrtf(s);
        norm = fmaxf(norm, 1e-12f);
        float zs = 0.f;
#pragma unroll
        for (int d = 0; d < D_DIM; ++d) {
            float v = row[d] / norm;
            zn[(size_t)r * D_DIM + d] = v;
            zs = fmaf(v, v, zs);
        }
        zz[r] = zs;
    }
}

__global__ __launch_bounds__(NTHREADS, 4)
void vq_main_basic(const float* __restrict__ zn, const float* __restrict__ zz,
                   const float* __restrict__ codebook, const float* __restrict__ cc,
                   float* __restrict__ pminv, int* __restrict__ pmini) {
    __shared__ float cb_lds[C_TILE * CB_PAD];
    __shared__ float zt[R_TILE * D_DIM];
    const int tid = threadIdx.x;
    const int rb = blockIdx.x & 255;
    const int slice = blockIdx.x >> 8;
    const int rg = tid >> 6;
    const int cg = tid & 63;
    const int row_base = rb * R_TILE;
    const int code_base = slice * SLICE_CODES_F;
    const int wrow = row_base + rg * 8;
    {
        float4 v = *reinterpret_cast<const float4*>(zn + (size_t)row_base * D_DIM + tid * 4);
        *reinterpret_cast<float4*>(&zt[tid * 4]) = v;
    }
    float zzr[8];
#pragma unroll
    for (int r = 0; r < 8; ++r) zzr[r] = zz[wrow + r];
    float minv[8]; int mini[8];
#pragma unroll
    for (int r = 0; r < 8; ++r) { minv[r] = 3.4e38f; mini[r] = 0; }
    for (int t = 0; t < N_TILES_F; ++t) {
        const int base = code_base + t * C_TILE;
        __syncthreads();
        {
            const float4* src = reinterpret_cast<const float4*>(codebook + (size_t)(base + tid) * D_DIM);
            float* dstf = &cb_lds[tid * CB_PAD];
#pragma unroll
            for (int k = 0; k < 8; ++k) *reinterpret_cast<float4*>(dstf + k * 4) = src[k];
        }
        __syncthreads();
        float acc[8][4];
#pragma unroll
        for (int r = 0; r < 8; ++r)
#pragma unroll
            for (int j = 0; j < 4; ++j) acc[r][j] = 0.f;
#pragma unroll
        for (int dc = 0; dc < 8; ++dc) {
            float4 cb4[4];
#pragma unroll
            for (int j = 0; j < 4; ++j)
                cb4[j] = *reinterpret_cast<const float4*>(&cb_lds[(cg + 64 * j) * CB_PAD + dc * 4]);
#pragma unroll
            for (int r = 0; r < 8; ++r) {
                const float4 zv = *reinterpret_cast<const float4*>(&zt[(rg * 8 + r) * D_DIM + dc * 4]);
#pragma unroll
                for (int j = 0; j < 4; ++j) {
                    float a = acc[r][j];
                    a = fmaf(zv.x, cb4[j].x, a);
                    a = fmaf(zv.y, cb4[j].y, a);
                    a = fmaf(zv.z, cb4[j].z, a);
                    a = fmaf(zv.w, cb4[j].w, a);
                    acc[r][j] = a;
                }
            }
        }
#pragma unroll
        for (int j = 0; j < 4; ++j) {
            const int code = base + cg + 64 * j;
            const float ccj = cc[code];
#pragma unroll
            for (int r = 0; r < 8; ++r) {
                float tsum = zzr[r] + ccj;
                float dist = fmaf(-2.f, acc[r][j], tsum);
                if (dist < minv[r]) { minv[r] = dist; mini[r] = code; }
            }
        }
    }
#pragma unroll
    for (int r = 0; r < 8; ++r) {
        float v = minv[r]; int i = mini[r];
#pragma unroll
        for (int off = 32; off >= 1; off >>= 1) {
            float ov = __shfl_xor(v, off);
            int   oi = __shfl_xor(i, off);
            if (ov < v || (ov == v && oi < i)) { v = ov; i = oi; }
        }
        minv[r] = v; mini[r] = i;
    }
    if (cg == 0) {
#pragma unroll
        for (int r = 0; r < 8; ++r) {
            pminv[slice * M_ROWS + wrow + r] = minv[r];
            pmini[slice * M_ROWS + wrow + r] = mini[r];
        }
    }
}

__global__ void vq_final_basic(const float* __restrict__ codebook,
                               const float* __restrict__ pminv,
                               const int* __restrict__ pmini,
                               float* __restrict__ zq, float* __restrict__ idx_out) {
    int row = blockIdx.x * NTHREADS + threadIdx.x;
    float bv = pminv[row];
    int   bi = pmini[row];
#pragma unroll
    for (int s = 1; s < NSLICE_F; ++s) {
        float v = pminv[s * M_ROWS + row];
        int   i = pmini[s * M_ROWS + row];
        if (v < bv || (v == bv && i < bi)) { bv = v; bi = i; }
    }
    idx_out[row] = (float)bi;
    const float4* src = reinterpret_cast<const float4*>(codebook + (size_t)bi * D_DIM);
    float4* dst = reinterpret_cast<float4*>(zq + (size_t)row * D_DIM);
#pragma unroll
    for (int k = 0; k < 8; ++k) dst[k] = src[k];
}

// ===========================================================================
static size_t ws_needed(int nslice) {
    return 4ull * (N_CODES + M_ROWS + 3ull * (size_t)nslice * M_ROWS) +
           4ull * (4 + M_ROWS) +
           2ull * (2ull * N_CODES * D_DIM + 2ull * M_ROWS * D_DIM);
}

template <int NS>
static void launch_mfma_path(const float* z, const float* codebook,
                             float* zn, float* zq_out, float* idx_out,
                             void* d_ws, hipStream_t stream) {
    float* cc    = (float*)d_ws;
    float* zz    = cc + N_CODES;
    float* pmax1 = zz + M_ROWS;
    float* pmax2 = pmax1 + (size_t)NS * M_ROWS;
    int*   pidx  = (int*)(pmax2 + (size_t)NS * M_ROWS);
    int*   todo_cnt = pidx + (size_t)NS * M_ROWS;
    int*   todo  = todo_cnt + 4;
    unsigned* chi = (unsigned*)(todo + M_ROWS);
    unsigned* clo = chi + (size_t)N_CODES * D_DIM / 2;
    unsigned* zhi = clo + (size_t)N_CODES * D_DIM / 2;
    unsigned* zlo = zhi + (size_t)M_ROWS * D_DIM / 2;

    // cleanup partials reuse pmax1/pidx (consumed by vq_merge before scan)
    float* cpmin = pmax1;
    int*   cpidx = pidx;

    vq_prep_pack<<<96, NTHREADS, 0, stream>>>(z, codebook, zn, zz, cc,
                                              chi, clo, zhi, zlo, todo_cnt);
    vq_mfma<NS><<<64 * NS, NTHREADS, 0, stream>>>(
        (const unsigned short*)zhi, (const unsigned short*)zlo,
        (const unsigned short*)chi, (const unsigned short*)clo,
        pmax1, pmax2, pidx);
    vq_merge<NS><<<M_ROWS / NTHREADS, NTHREADS, 0, stream>>>(
        codebook, pmax1, pmax2, pidx, zq_out, idx_out, todo_cnt, todo);
    vq_cleanup_scan<<<SCAN_SLOTS * NCHUNK, NTHREADS, 0, stream>>>(
        zn, zz, codebook, cc, todo_cnt, todo, cpmin, cpidx);
    vq_cleanup_final<<<32, NTHREADS, 0, stream>>>(
        codebook, todo_cnt, todo, cpmin, cpidx, zq_out, idx_out);
}

extern "C" void kernel_launch(void* const* d_in, const int* in_sizes, int n_in,
                              void* d_out, int out_size, void* d_ws, size_t ws_size,
                              hipStream_t stream) {
    const float* z        = (const float*)d_in[0];   // [8,1024,32]
    const float* codebook = (const float*)d_in[1];   // [16384,32]

    float* out     = (float*)d_out;
    float* zq_out  = out;                            // 262144 floats
    float* idx_out = out + (size_t)M_ROWS * D_DIM;   // 8192 floats
    float* zn      = zq_out;                         // zn lives in zq region

    if (ws_size >= ws_needed(16)) {
        launch_mfma_path<16>(z, codebook, zn, zq_out, idx_out, d_ws, stream);
    } else {
        // Fallback: proven R3 path (~350 KB ws)
        float* cc    = (float*)d_ws;
        float* zz    = cc + N_CODES;
        float* pminv = zz + M_ROWS;
        int*   pmini = (int*)(pminv + (size_t)NSLICE_F * M_ROWS);

        vq_prep_basic<<<96, NTHREADS, 0, stream>>>(z, codebook, zn, zz, cc);
        vq_main_basic<<<256 * NSLICE_F, NTHREADS, 0, stream>>>(zn, zz, codebook, cc,
                                                               pminv, pmini);
        vq_final_basic<<<M_ROWS / NTHREADS, NTHREADS, 0, stream>>>(codebook, pminv,
                                                                   pmini, zq_out, idx_out);
    }
}

// Round 15
// 65.159 us; speedup vs baseline: 9.4890x; 1.1329x over previous
//
#include <hip/hip_runtime.h>
#include <math.h>

// Problem constants
#define M_ROWS   8192     // B*S
#define N_CODES  16384
#define D_DIM    32
#define NTHREADS 256

// Certification margin. With the 4-pass hi/lo MFMA (hh+hl+lh+ll) the key error
// budget is: 2 dists x (2*residual-trunc 7.6e-6 + fp32 accum ~4e-6) + ref-chain
// difference ~5e-6 + raw-dot cc-drop 8e-7  =>  ~2.9e-5 worst case.
// Margin 8e-5 = 2.7x cushion (same ratio as the validated 2e-4 / 3-pass setup).
#define DELTA_MARGIN  8e-5f

// ===== cleanup parameters =====
#define NCHUNK       16
#define CHUNK_CODES  (N_CODES / NCHUNK)       // 1024
#define SCAN_SLOTS   256                       // row-slot stride in scan grid

typedef short bf16x8 __attribute__((ext_vector_type(8)));  // 8 bf16
typedef float f32x4  __attribute__((ext_vector_type(4)));

// round-to-nearest-even fp32 -> bf16 bits
__device__ inline unsigned short bf16_rne(float f) {
    unsigned u = __float_as_uint(f);
    unsigned r = u + 0x7FFFu + ((u >> 16) & 1u);
    return (unsigned short)(r >> 16);
}

__device__ inline void pack_pair(float f0, float f1, unsigned& hi, unsigned& lo) {
    unsigned short h0 = bf16_rne(f0), h1 = bf16_rne(f1);
    float r0 = f0 - __uint_as_float((unsigned)h0 << 16);
    float r1 = f1 - __uint_as_float((unsigned)h1 << 16);
    unsigned short l0 = bf16_rne(r0), l1 = bf16_rne(r1);
    hi = (unsigned)h0 | ((unsigned)h1 << 16);
    lo = (unsigned)l0 | ((unsigned)l1 << 16);
}

// fp32 -> order-preserving u32 (ascending float => ascending uint)
__device__ inline unsigned sortable_u32(float f) {
    unsigned u = __float_as_uint(f);
    return (u & 0x80000000u) ? ~u : (u | 0x80000000u);
}

// ---------------------------------------------------------------------------
// Prep+pack v4: FOUR THREADS PER ROW (384 blocks). Each thread redundantly
// loads its full row and recomputes the identical sequential fmaf chains
// (bit-exact norm/cc vs the validated 1-thread-per-row version), but packs and
// stores only its 8-element slice -> 4x parallelism on the store/pack side.
//   rows 0..N_CODES-1: cc + codebook hi/lo pack
//   rows N_CODES..   : normalize z -> zn (d_out), zz, z hi/lo pack
// ---------------------------------------------------------------------------
__global__ void vq_prep_pack(const float* __restrict__ z,
                             const float* __restrict__ codebook,
                             float* __restrict__ zn, float* __restrict__ zz,
                             float* __restrict__ cc,
                             unsigned* __restrict__ chi, unsigned* __restrict__ clo,
                             unsigned* __restrict__ zhi, unsigned* __restrict__ zlo,
                             int* __restrict__ todo_cnt) {
    int gid  = blockIdx.x * NTHREADS + threadIdx.x;   // 0..98303
    int row  = gid >> 2;                              // 0..24575
    int part = gid & 3;                               // 8-element slice
    if (gid == 0) *todo_cnt = 0;

    if (row < N_CODES) {
        const float4* r4 = reinterpret_cast<const float4*>(codebook + (size_t)row * D_DIM);
        float4 v[8];
#pragma unroll
        for (int h = 0; h < 8; ++h) v[h] = r4[h];
        float s = 0.f;
#pragma unroll
        for (int h = 0; h < 8; ++h) {   // full-row sequential chain (exact order)
            s = fmaf(v[h].x, v[h].x, s);
            s = fmaf(v[h].y, v[h].y, s);
            s = fmaf(v[h].z, v[h].z, s);
            s = fmaf(v[h].w, v[h].w, s);
        }
        if (part == 0) cc[row] = s;
        // pack this thread's 2 float4s (elements part*8 .. part*8+7)
#pragma unroll
        for (int k = 0; k < 2; ++k) {
            int h = part * 2 + k;
            unsigned hi0, lo0, hi1, lo1;
            pack_pair(v[h].x, v[h].y, hi0, lo0);
            pack_pair(v[h].z, v[h].w, hi1, lo1);
            chi[row * 16 + 2 * h]     = hi0;  clo[row * 16 + 2 * h]     = lo0;
            chi[row * 16 + 2 * h + 1] = hi1;  clo[row * 16 + 2 * h + 1] = lo1;
        }
    } else {
        int r = row - N_CODES;                 // 0..8191
        const float4* r4 = reinterpret_cast<const float4*>(z + (size_t)r * D_DIM);
        float4 v[8];
#pragma unroll
        for (int h = 0; h < 8; ++h) v[h] = r4[h];
        float s = 0.f;
#pragma unroll
        for (int h = 0; h < 8; ++h) {
            s = fmaf(v[h].x, v[h].x, s);
            s = fmaf(v[h].y, v[h].y, s);
            s = fmaf(v[h].z, v[h].z, s);
            s = fmaf(v[h].w, v[h].w, s);
        }
        float norm = sqrtf(s);
        norm = fmaxf(norm, 1e-12f);
        // full-row normalized values + sequential zs chain (identical rounding)
        float zs = 0.f;
        float4 w[8];
#pragma unroll
        for (int h = 0; h < 8; ++h) {
            w[h].x = v[h].x / norm;            // IEEE division, matches reference
            w[h].y = v[h].y / norm;
            w[h].z = v[h].z / norm;
            w[h].w = v[h].w / norm;
            zs = fmaf(w[h].x, w[h].x, zs);
            zs = fmaf(w[h].y, w[h].y, zs);
            zs = fmaf(w[h].z, w[h].z, zs);
            zs = fmaf(w[h].w, w[h].w, zs);
        }
        if (part == 0) zz[r] = zs;
        float4* zn4 = reinterpret_cast<float4*>(zn + (size_t)r * D_DIM);
#pragma unroll
        for (int k = 0; k < 2; ++k) {
            int h = part * 2 + k;
            zn4[h] = w[h];
            unsigned hi0, lo0, hi1, lo1;
            pack_pair(w[h].x, w[h].y, hi0, lo0);
            pack_pair(w[h].z, w[h].w, hi1, lo1);
            zhi[r * 16 + 2 * h]     = hi0;  zlo[r * 16 + 2 * h]     = lo0;
            zhi[r * 16 + 2 * h + 1] = hi1;  zlo[r * 16 + 2 * h + 1] = lo1;
        }
    }
}

// ---------------------------------------------------------------------------
// MFMA main v7 (R14 structure + lo*lo 4th pass):
//  - key = RAW DOT with full 4-pass hi/lo product (hh+hl+lh+ll) -> key err
//    ~1.2e-5, enabling the tighter 8e-5 margin (2.5x fewer cleanup rows).
//  - First MFMA of each chain takes a persistent zero quad as C (no init).
//  - Prefetch depth 1 pair. NO unroll pragma (R13 spill lesson).
// A: lane holds row (l&15), k=(l>>4)*8+i. D: col=l&15, row=(l>>4)*4+reg.
// ---------------------------------------------------------------------------
template <int NS>
__global__ __launch_bounds__(NTHREADS, 4)
void vq_mfma(const unsigned short* __restrict__ zhi,
             const unsigned short* __restrict__ zlo,
             const unsigned short* __restrict__ chi,
             const unsigned short* __restrict__ clo,
             float* __restrict__ pmax1, float* __restrict__ pmax2,
             int* __restrict__ pidx) {
    constexpr int SLICE_CODES = N_CODES / NS;   // 1024 at NS=16
    constexpr int NPAIR = SLICE_CODES / 32;     // 32 double-tiles

    const int tid  = threadIdx.x;
    const int wave = tid >> 6;
    const int lane = tid & 63;
    const int rb    = blockIdx.x & 63;
    const int slice = blockIdx.x >> 6;

    const int row_w = rb * 128 + wave * 32;    // wave's 32 rows (2 row-tiles)
    const int l15 = lane & 15;
    const int kg  = lane >> 4;                 // k-group 0..3
    const int kc  = kg * 8;

    const bf16x8 a_hi0 = *reinterpret_cast<const bf16x8*>(zhi + (size_t)(row_w + l15) * 32 + kc);
    const bf16x8 a_lo0 = *reinterpret_cast<const bf16x8*>(zlo + (size_t)(row_w + l15) * 32 + kc);
    const bf16x8 a_hi1 = *reinterpret_cast<const bf16x8*>(zhi + (size_t)(row_w + 16 + l15) * 32 + kc);
    const bf16x8 a_lo1 = *reinterpret_cast<const bf16x8*>(zlo + (size_t)(row_w + 16 + l15) * 32 + kc);

    const f32x4 zero4 = {0.f, 0.f, 0.f, 0.f};

    float max1[8], max2[8];
    int   idx1[8];
#pragma unroll
    for (int q = 0; q < 8; ++q) { max1[q] = -3.4e38f; max2[q] = -3.4e38f; idx1[q] = 0x7FFFFFFF; }

    // argmax(top-2) update: 4 VALU per element
    auto argup = [&](const f32x4& accA, const f32x4& accB, int code) {
#pragma unroll
        for (int e = 0; e < 4; ++e) {
            float s0 = accA[e];
            max2[e] = __builtin_amdgcn_fmed3f(s0, max1[e], max2[e]);
            bool gt0 = s0 > max1[e];
            max1[e] = gt0 ? s0 : max1[e];
            idx1[e] = gt0 ? code : idx1[e];

            float s1 = accB[e];
            max2[4 + e] = __builtin_amdgcn_fmed3f(s1, max1[4 + e], max2[4 + e]);
            bool gt1 = s1 > max1[4 + e];
            max1[4 + e] = gt1 ? s1 : max1[4 + e];
            idx1[4 + e] = gt1 ? code : idx1[4 + e];
        }
    };
    // 16 MFMAs for one tile-pair: 4 independent chains of 4 (ll,lh,hl,hh),
    // step-interleaved; first MFMA of each chain reads zero4 directly as C.
    auto pair_compute = [&](const bf16x8& b0h, const bf16x8& b0l,
                            const bf16x8& b1h, const bf16x8& b1l, int code) {
        f32x4 a00 = __builtin_amdgcn_mfma_f32_16x16x32_bf16(a_lo0, b0l, zero4, 0, 0, 0);
        f32x4 a01 = __builtin_amdgcn_mfma_f32_16x16x32_bf16(a_lo1, b0l, zero4, 0, 0, 0);
        f32x4 a10 = __builtin_amdgcn_mfma_f32_16x16x32_bf16(a_lo0, b1l, zero4, 0, 0, 0);
        f32x4 a11 = __builtin_amdgcn_mfma_f32_16x16x32_bf16(a_lo1, b1l, zero4, 0, 0, 0);
        a00 = __builtin_amdgcn_mfma_f32_16x16x32_bf16(a_lo0, b0h, a00, 0, 0, 0);
        a01 = __builtin_amdgcn_mfma_f32_16x16x32_bf16(a_lo1, b0h, a01, 0, 0, 0);
        a10 = __builtin_amdgcn_mfma_f32_16x16x32_bf16(a_lo0, b1h, a10, 0, 0, 0);
        a11 = __builtin_amdgcn_mfma_f32_16x16x32_bf16(a_lo1, b1h, a11, 0, 0, 0);
        a00 = __builtin_amdgcn_mfma_f32_16x16x32_bf16(a_hi0, b0l, a00, 0, 0, 0);
        a01 = __builtin_amdgcn_mfma_f32_16x16x32_bf16(a_hi1, b0l, a01, 0, 0, 0);
        a10 = __builtin_amdgcn_mfma_f32_16x16x32_bf16(a_hi0, b1l, a10, 0, 0, 0);
        a11 = __builtin_amdgcn_mfma_f32_16x16x32_bf16(a_hi1, b1l, a11, 0, 0, 0);
        a00 = __builtin_amdgcn_mfma_f32_16x16x32_bf16(a_hi0, b0h, a00, 0, 0, 0);
        a01 = __builtin_amdgcn_mfma_f32_16x16x32_bf16(a_hi1, b0h, a01, 0, 0, 0);
        a10 = __builtin_amdgcn_mfma_f32_16x16x32_bf16(a_hi0, b1h, a10, 0, 0, 0);
        a11 = __builtin_amdgcn_mfma_f32_16x16x32_bf16(a_hi1, b1h, a11, 0, 0, 0);
        argup(a00, a01, code);
        argup(a10, a11, code + 16);
    };

    // software-pipelined pair loop: prefetch p+1 during p (R10/R12/R14-proven)
    int code = slice * SLICE_CODES + l15;
    bf16x8 b0h = *reinterpret_cast<const bf16x8*>(chi + (size_t)code * 32 + kc);
    bf16x8 b0l = *reinterpret_cast<const bf16x8*>(clo + (size_t)code * 32 + kc);
    bf16x8 b1h = *reinterpret_cast<const bf16x8*>(chi + (size_t)(code + 16) * 32 + kc);
    bf16x8 b1l = *reinterpret_cast<const bf16x8*>(clo + (size_t)(code + 16) * 32 + kc);

    for (int p = 0; p < NPAIR - 1; ++p) {
        const int ncode = code + 32;
        const bf16x8 nb0h = *reinterpret_cast<const bf16x8*>(chi + (size_t)ncode * 32 + kc);
        const bf16x8 nb0l = *reinterpret_cast<const bf16x8*>(clo + (size_t)ncode * 32 + kc);
        const bf16x8 nb1h = *reinterpret_cast<const bf16x8*>(chi + (size_t)(ncode + 16) * 32 + kc);
        const bf16x8 nb1l = *reinterpret_cast<const bf16x8*>(clo + (size_t)(ncode + 16) * 32 + kc);

        pair_compute(b0h, b0l, b1h, b1l, code);

        b0h = nb0h; b0l = nb0l; b1h = nb1h; b1l = nb1l; code = ncode;
    }
    pair_compute(b0h, b0l, b1h, b1l, code);   // peeled last pair

    // merge top-2 (max) across the 16 column-lanes
#pragma unroll
    for (int q = 0; q < 8; ++q) {
        float m1 = max1[q], m2 = max2[q];
        int   i1 = idx1[q];
#pragma unroll
        for (int off = 1; off < 16; off <<= 1) {
            float o1 = __shfl_xor(m1, off);
            float o2 = __shfl_xor(m2, off);
            int   oi = __shfl_xor(i1, off);
            float nm2 = fmaxf(fminf(m1, o1), fmaxf(m2, o2));
            if (o1 > m1 || (o1 == m1 && oi < i1)) { m1 = o1; i1 = oi; }
            m2 = nm2;
        }
        max1[q] = m1; max2[q] = m2; idx1[q] = i1;
    }
    if (l15 == 0) {
#pragma unroll
        for (int q = 0; q < 8; ++q) {
            const int rt = q >> 2, e = q & 3;
            const int row = row_w + rt * 16 + kg * 4 + e;
            pmax1[slice * M_ROWS + row] = max1[q];
            pmax2[slice * M_ROWS + row] = max2[q];
            pidx [slice * M_ROWS + row] = idx1[q];
        }
    }
}

// ---------------------------------------------------------------------------
// Merge slices (max-key = raw dot); certified rows finalize; rest -> todo
// and rbest[row] initialized to all-ones for the scan's atomicMin.
// ---------------------------------------------------------------------------
template <int NS>
__global__ void vq_merge(const float* __restrict__ codebook,
                         const float* __restrict__ pmax1,
                         const float* __restrict__ pmax2,
                         const int* __restrict__ pidx,
                         float* __restrict__ zq, float* __restrict__ idx_out,
                         int* __restrict__ todo_cnt, int* __restrict__ todo,
                         unsigned long long* __restrict__ rbest) {
    const int row = blockIdx.x * NTHREADS + threadIdx.x;
    float m1 = pmax1[row], m2 = pmax2[row];
    int   i1 = pidx[row];
#pragma unroll
    for (int s = 1; s < NS; ++s) {
        float o1 = pmax1[s * M_ROWS + row];
        float o2 = pmax2[s * M_ROWS + row];
        int   oi = pidx [s * M_ROWS + row];
        float nm2 = fmaxf(fminf(m1, o1), fmaxf(m2, o2));
        if (o1 > m1) { m1 = o1; i1 = oi; }
        m2 = nm2;
    }
    if (2.0f * (m1 - m2) > DELTA_MARGIN) {
        idx_out[row] = (float)i1;
        const float4* src = reinterpret_cast<const float4*>(codebook + (size_t)i1 * D_DIM);
        float4* dst = reinterpret_cast<float4*>(zq + (size_t)row * D_DIM);
#pragma unroll
        for (int k = 0; k < 8; ++k) dst[k] = src[k];
    } else {
        rbest[row] = 0xFFFFFFFFFFFFFFFFull;
        int p = atomicAdd(todo_cnt, 1);
        todo[p] = row;
    }
}

// ---------------------------------------------------------------------------
// Cleanup SCAN v2: work item = (todo-slot, chunk). Exact R3-proven fp32
// chain; per-thread best packed as u64 key = (sortable(dist)<<32)|code
// (u64 < gives min dist, tie -> lowest code: numpy semantics). Wave
// butterfly then one device-scope atomicMin per wave into rbest[row].
// ---------------------------------------------------------------------------
__global__ __launch_bounds__(NTHREADS)
void vq_cleanup_scan(const float* __restrict__ zn, const float* __restrict__ zz,
                     const float* __restrict__ codebook, const float* __restrict__ cc,
                     const int* __restrict__ todo_cnt, const int* __restrict__ todo,
                     unsigned long long* __restrict__ rbest) {
    const int n = *todo_cnt;
    const int chunk = blockIdx.x & (NCHUNK - 1);
    const int slot  = blockIdx.x >> 4;            // 0..SCAN_SLOTS-1
    const int tid   = threadIdx.x;
    const int cbase = chunk * CHUNK_CODES;

    for (int i = slot; i < n; i += SCAN_SLOTS) {
        const int row = todo[i];

        float zr[D_DIM];
#pragma unroll
        for (int d = 0; d < D_DIM; ++d) zr[d] = zn[(size_t)row * D_DIM + d];
        const float zzv = zz[row];

        unsigned long long best = 0xFFFFFFFFFFFFFFFFull;
#pragma unroll
        for (int k = 0; k < CHUNK_CODES / NTHREADS; ++k) {   // 4 iters
            const int c = cbase + tid + (k << 8);            // ascending per thread
            const float4* cb = reinterpret_cast<const float4*>(codebook + (size_t)c * D_DIM);
            float dot = 0.f;
#pragma unroll
            for (int h = 0; h < 8; ++h) {
                float4 v = cb[h];
                dot = fmaf(zr[4 * h + 0], v.x, dot);
                dot = fmaf(zr[4 * h + 1], v.y, dot);
                dot = fmaf(zr[4 * h + 2], v.z, dot);
                dot = fmaf(zr[4 * h + 3], v.w, dot);
            }
            float t = zzv + cc[c];
            float dist = fmaf(-2.f, dot, t);
            unsigned long long key =
                ((unsigned long long)sortable_u32(dist) << 32) | (unsigned)c;
            best = (key < best) ? key : best;
        }

#pragma unroll
        for (int off = 32; off >= 1; off >>= 1) {
            unsigned long long ob = __shfl_xor(best, off);
            best = (ob < best) ? ob : best;
        }
        if ((tid & 63) == 0) {
            atomicMin(&rbest[row], best);   // device-scope (G12)
        }
    }
}

// ---------------------------------------------------------------------------
// Cleanup FINAL v2: one thread per todo row; unpack rbest, write idx + zq.
// ---------------------------------------------------------------------------
__global__ __launch_bounds__(NTHREADS)
void vq_cleanup_final(const float* __restrict__ codebook,
                      const int* __restrict__ todo_cnt, const int* __restrict__ todo,
                      const unsigned long long* __restrict__ rbest,
                      float* __restrict__ zq, float* __restrict__ idx_out) {
    const int n = *todo_cnt;
    for (int i = blockIdx.x * NTHREADS + threadIdx.x; i < n; i += gridDim.x * NTHREADS) {
        const int row = todo[i];
        const int bi = (int)(unsigned)(rbest[row] & 0xFFFFFFFFull);
        idx_out[row] = (float)bi;
        const float4* src = reinterpret_cast<const float4*>(codebook + (size_t)bi * D_DIM);
        float4* dst = reinterpret_cast<float4*>(zq + (size_t)row * D_DIM);
#pragma unroll
        for (int k = 0; k < 8; ++k) dst[k] = src[k];
    }
}

// ===========================================================================
// ===== Fallback path (verbatim R3, proven 175 us / absmax 0) ==============
// ===========================================================================
#define R_TILE   32
#define NSLICE_F 4
#define SLICE_CODES_F (N_CODES / NSLICE_F)
#define C_TILE   256
#define N_TILES_F (SLICE_CODES_F / C_TILE)
#define CB_PAD   36

__global__ void vq_prep_basic(const float* __restrict__ z,
                              const float* __restrict__ codebook,
                              float* __restrict__ zn,
                              float* __restrict__ zz,
                              float* __restrict__ cc) {
    int gid = blockIdx.x * NTHREADS + threadIdx.x;
    if (blockIdx.x < 64) {
        const float* row = codebook + (size_t)gid * D_DIM;
        float s = 0.f;
#pragma unroll
        for (int d = 0; d < D_DIM; ++d) s = fmaf(row[d], row[d], s);
        cc[gid] = s;
    } else {
        int r = gid - N_CODES;
        const float* row = z + (size_t)r * D_DIM;
        float s = 0.f;
#pragma unroll
        for (int d = 0; d < D_DIM; ++d) { float v = row[d]; s = fmaf(v, v, s); }
        float norm = sqrtf(s);
        norm = fmaxf(norm, 1e-12f);
        float zs = 0.f;
#pragma unroll
        for (int d = 0; d < D_DIM; ++d) {
            float v = row[d] / norm;
            zn[(size_t)r * D_DIM + d] = v;
            zs = fmaf(v, v, zs);
        }
        zz[r] = zs;
    }
}

__global__ __launch_bounds__(NTHREADS, 4)
void vq_main_basic(const float* __restrict__ zn, const float* __restrict__ zz,
                   const float* __restrict__ codebook, const float* __restrict__ cc,
                   float* __restrict__ pminv, int* __restrict__ pmini) {
    __shared__ float cb_lds[C_TILE * CB_PAD];
    __shared__ float zt[R_TILE * D_DIM];
    const int tid = threadIdx.x;
    const int rb = blockIdx.x & 255;
    const int slice = blockIdx.x >> 8;
    const int rg = tid >> 6;
    const int cg = tid & 63;
    const int row_base = rb * R_TILE;
    const int code_base = slice * SLICE_CODES_F;
    const int wrow = row_base + rg * 8;
    {
        float4 v = *reinterpret_cast<const float4*>(zn + (size_t)row_base * D_DIM + tid * 4);
        *reinterpret_cast<float4*>(&zt[tid * 4]) = v;
    }
    float zzr[8];
#pragma unroll
    for (int r = 0; r < 8; ++r) zzr[r] = zz[wrow + r];
    float minv[8]; int mini[8];
#pragma unroll
    for (int r = 0; r < 8; ++r) { minv[r] = 3.4e38f; mini[r] = 0; }
    for (int t = 0; t < N_TILES_F; ++t) {
        const int base = code_base + t * C_TILE;
        __syncthreads();
        {
            const float4* src = reinterpret_cast<const float4*>(codebook + (size_t)(base + tid) * D_DIM);
            float* dstf = &cb_lds[tid * CB_PAD];
#pragma unroll
            for (int k = 0; k < 8; ++k) *reinterpret_cast<float4*>(dstf + k * 4) = src[k];
        }
        __syncthreads();
        float acc[8][4];
#pragma unroll
        for (int r = 0; r < 8; ++r)
#pragma unroll
            for (int j = 0; j < 4; ++j) acc[r][j] = 0.f;
#pragma unroll
        for (int dc = 0; dc < 8; ++dc) {
            float4 cb4[4];
#pragma unroll
            for (int j = 0; j < 4; ++j)
                cb4[j] = *reinterpret_cast<const float4*>(&cb_lds[(cg + 64 * j) * CB_PAD + dc * 4]);
#pragma unroll
            for (int r = 0; r < 8; ++r) {
                const float4 zv = *reinterpret_cast<const float4*>(&zt[(rg * 8 + r) * D_DIM + dc * 4]);
#pragma unroll
                for (int j = 0; j < 4; ++j) {
                    float a = acc[r][j];
                    a = fmaf(zv.x, cb4[j].x, a);
                    a = fmaf(zv.y, cb4[j].y, a);
                    a = fmaf(zv.z, cb4[j].z, a);
                    a = fmaf(zv.w, cb4[j].w, a);
                    acc[r][j] = a;
                }
            }
        }
#pragma unroll
        for (int j = 0; j < 4; ++j) {
            const int code = base + cg + 64 * j;
            const float ccj = cc[code];
#pragma unroll
            for (int r = 0; r < 8; ++r) {
                float tsum = zzr[r] + ccj;
                float dist = fmaf(-2.f, acc[r][j], tsum);
                if (dist < minv[r]) { minv[r] = dist; mini[r] = code; }
            }
        }
    }
#pragma unroll
    for (int r = 0; r < 8; ++r) {
        float v = minv[r]; int i = mini[r];
#pragma unroll
        for (int off = 32; off >= 1; off >>= 1) {
            float ov = __shfl_xor(v, off);
            int   oi = __shfl_xor(i, off);
            if (ov < v || (ov == v && oi < i)) { v = ov; i = oi; }
        }
        minv[r] = v; mini[r] = i;
    }
    if (cg == 0) {
#pragma unroll
        for (int r = 0; r < 8; ++r) {
            pminv[slice * M_ROWS + wrow + r] = minv[r];
            pmini[slice * M_ROWS + wrow + r] = mini[r];
        }
    }
}

__global__ void vq_final_basic(const float* __restrict__ codebook,
                               const float* __restrict__ pminv,
                               const int* __restrict__ pmini,
                               float* __restrict__ zq, float* __restrict__ idx_out) {
    int row = blockIdx.x * NTHREADS + threadIdx.x;
    float bv = pminv[row];
    int   bi = pmini[row];
#pragma unroll
    for (int s = 1; s < NSLICE_F; ++s) {
        float v = pminv[s * M_ROWS + row];
        int   i = pmini[s * M_ROWS + row];
        if (v < bv || (v == bv && i < bi)) { bv = v; bi = i; }
    }
    idx_out[row] = (float)bi;
    const float4* src = reinterpret_cast<const float4*>(codebook + (size_t)bi * D_DIM);
    float4* dst = reinterpret_cast<float4*>(zq + (size_t)row * D_DIM);
#pragma unroll
    for (int k = 0; k < 8; ++k) dst[k] = src[k];
}

// ===========================================================================
static size_t ws_needed(int nslice) {
    // floats: cc, zz, pmax1, pmax2 ; ints: pidx, todo_cnt, todo ;
    // u64: rbest ; u16: chi, clo, zhi, zlo
    return 4ull * (N_CODES + M_ROWS + 3ull * (size_t)nslice * M_ROWS) +
           4ull * (4 + M_ROWS) +
           8ull * M_ROWS +
           2ull * (2ull * N_CODES * D_DIM + 2ull * M_ROWS * D_DIM) + 4096;
}

template <int NS>
static void launch_mfma_path(const float* z, const float* codebook,
                             float* zn, float* zq_out, float* idx_out,
                             void* d_ws, hipStream_t stream) {
    float* cc    = (float*)d_ws;
    float* zz    = cc + N_CODES;
    float* pmax1 = zz + M_ROWS;
    float* pmax2 = pmax1 + (size_t)NS * M_ROWS;
    int*   pidx  = (int*)(pmax2 + (size_t)NS * M_ROWS);
    int*   todo_cnt = pidx + (size_t)NS * M_ROWS;
    int*   todo  = todo_cnt + 4;
    unsigned long long* rbest = (unsigned long long*)(todo + M_ROWS);  // 8B-aligned
    unsigned* chi = (unsigned*)(rbest + M_ROWS);
    unsigned* clo = chi + (size_t)N_CODES * D_DIM / 2;
    unsigned* zhi = clo + (size_t)N_CODES * D_DIM / 2;
    unsigned* zlo = zhi + (size_t)M_ROWS * D_DIM / 2;

    vq_prep_pack<<<384, NTHREADS, 0, stream>>>(z, codebook, zn, zz, cc,
                                               chi, clo, zhi, zlo, todo_cnt);
    vq_mfma<NS><<<64 * NS, NTHREADS, 0, stream>>>(
        (const unsigned short*)zhi, (const unsigned short*)zlo,
        (const unsigned short*)chi, (const unsigned short*)clo,
        pmax1, pmax2, pidx);
    vq_merge<NS><<<M_ROWS / NTHREADS, NTHREADS, 0, stream>>>(
        codebook, pmax1, pmax2, pidx, zq_out, idx_out, todo_cnt, todo, rbest);
    vq_cleanup_scan<<<SCAN_SLOTS * NCHUNK, NTHREADS, 0, stream>>>(
        zn, zz, codebook, cc, todo_cnt, todo, rbest);
    vq_cleanup_final<<<32, NTHREADS, 0, stream>>>(
        codebook, todo_cnt, todo, rbest, zq_out, idx_out);
}

extern "C" void kernel_launch(void* const* d_in, const int* in_sizes, int n_in,
                              void* d_out, int out_size, void* d_ws, size_t ws_size,
                              hipStream_t stream) {
    const float* z        = (const float*)d_in[0];   // [8,1024,32]
    const float* codebook = (const float*)d_in[1];   // [16384,32]

    float* out     = (float*)d_out;
    float* zq_out  = out;                            // 262144 floats
    float* idx_out = out + (size_t)M_ROWS * D_DIM;   // 8192 floats
    float* zn      = zq_out;                         // zn lives in zq region

    if (ws_size >= ws_needed(16)) {
        launch_mfma_path<16>(z, codebook, zn, zq_out, idx_out, d_ws, stream);
    } else {
        // Fallback: proven R3 path (~350 KB ws)
        float* cc    = (float*)d_ws;
        float* zz    = cc + N_CODES;
        float* pminv = zz + M_ROWS;
        int*   pmini = (int*)(pminv + (size_t)NSLICE_F * M_ROWS);

        vq_prep_basic<<<96, NTHREADS, 0, stream>>>(z, codebook, zn, zz, cc);
        vq_main_basic<<<256 * NSLICE_F, NTHREADS, 0, stream>>>(zn, zz, codebook, cc,
                                                               pminv, pmini);
        vq_final_basic<<<M_ROWS / NTHREADS, NTHREADS, 0, stream>>>(codebook, pminv,
                                                                   pmini, zq_out, idx_out);
    }
}